// Round 1
// baseline (4809.007 us; speedup 1.0000x reference)
//
#include <hip/hip_runtime.h>
#include <math.h>

#define NN 100000
#define EE 1600000
#define D 128
#define ROWS 16

// ---------------- one-time: transpose gate weights [128][256] -> [256][128] ----------------
__global__ __launch_bounds__(128) void transpose_gates(
    const float* __restrict__ ugW, const float* __restrict__ rgW,
    float* __restrict__ ugWT, float* __restrict__ rgWT) {
  int c = blockIdx.x;      // 0..255
  int o = threadIdx.x;     // 0..127
  ugWT[c * 128 + o] = ugW[o * 256 + c];
  rgWT[c * 128 + o] = rgW[o * 256 + c];
}

// ---------------- h0 = X @ W + b ----------------
__global__ __launch_bounds__(128) void init_h(
    const float* __restrict__ X, const float* __restrict__ W,
    const float* __restrict__ b, float* __restrict__ h) {
  __shared__ float a_t[D * 16];  // [k][i], row stride 16 floats (64B, b128-aligned)
  const int row0 = blockIdx.x * ROWS;
  const int tid = threadIdx.x;
  const int i = tid & 15, cc = tid >> 4;  // cc in 0..7

  const float4* xr = (const float4*)(X + (size_t)(row0 + i) * D);
#pragma unroll
  for (int u4 = 0; u4 < 4; ++u4) {
    float4 v = xr[cc * 4 + u4];
    int c = cc * 16 + u4 * 4;
    a_t[(c + 0) * 16 + i] = v.x;
    a_t[(c + 1) * 16 + i] = v.y;
    a_t[(c + 2) * 16 + i] = v.z;
    a_t[(c + 3) * 16 + i] = v.w;
  }
  __syncthreads();

  const int j = tid;  // output column
  float acc[ROWS];
  const float bj = b[j];
#pragma unroll
  for (int r = 0; r < ROWS; ++r) acc[r] = bj;

  for (int k = 0; k < D; ++k) {
    float w = W[k * D + j];
    const float4* av = (const float4*)(a_t + k * 16);
    float4 a0 = av[0], a1 = av[1], a2 = av[2], a3 = av[3];
    float ga[16] = {a0.x, a0.y, a0.z, a0.w, a1.x, a1.y, a1.z, a1.w,
                    a2.x, a2.y, a2.z, a2.w, a3.x, a3.y, a3.z, a3.w};
#pragma unroll
    for (int r = 0; r < ROWS; ++r) acc[r] += ga[r] * w;
  }
#pragma unroll
  for (int r = 0; r < ROWS; ++r) h[(size_t)(row0 + r) * D + j] = acc[r];
}

// ---------------- m[row] += w_e * h[col], one wave per edge ----------------
__global__ __launch_bounds__(256) void spmm_scatter(
    const int* __restrict__ erow, const int* __restrict__ ecol,
    const float* __restrict__ ew, const float* __restrict__ h,
    float* __restrict__ m) {
  const int lane = threadIdx.x & 63;
  const int wave0 = blockIdx.x * 4 + (threadIdx.x >> 6);
  const int stride = gridDim.x * 4;
  for (int e = wave0; e < EE; e += stride) {
    int r = erow[e];
    int c = ecol[e];
    float w = ew[e];
    float2 hv = ((const float2*)(h + (size_t)c * D))[lane];
    float* mp = m + (size_t)r * D + lane * 2;
    unsafeAtomicAdd(mp + 0, w * hv.x);
    unsafeAtomicAdd(mp + 1, w * hv.y);
  }
}

// ---------------- gates + candidate + in-place h update ----------------
__global__ __launch_bounds__(128) void gate_update(
    const float* __restrict__ m,
    const float* __restrict__ ugWT, const float* __restrict__ rgWT,
    const float* __restrict__ ugb, const float* __restrict__ rgb,
    const float* __restrict__ CW, float* __restrict__ h) {
  __shared__ float g_t[2 * D * 16];   // [c][i], c in 0..255, stride 16  (16 KB)
  __shared__ float rh_t[D * 20];      // [k][i], stride 20 (80B, b128-aligned) (10 KB)
  const int row0 = blockIdx.x * ROWS;
  const int tid = threadIdx.x;
  const int i = tid & 15, cc = tid >> 4;

  // stage h-tile and m-tile transposed into g_t = [h | m]
  const float4* hr = (const float4*)(h + (size_t)(row0 + i) * D);
  const float4* mr = (const float4*)(m + (size_t)(row0 + i) * D);
#pragma unroll
  for (int u4 = 0; u4 < 4; ++u4) {
    float4 v = hr[cc * 4 + u4];
    int c = cc * 16 + u4 * 4;
    g_t[(c + 0) * 16 + i] = v.x;
    g_t[(c + 1) * 16 + i] = v.y;
    g_t[(c + 2) * 16 + i] = v.z;
    g_t[(c + 3) * 16 + i] = v.w;
    float4 vm = mr[cc * 4 + u4];
    int c2 = D + c;
    g_t[(c2 + 0) * 16 + i] = vm.x;
    g_t[(c2 + 1) * 16 + i] = vm.y;
    g_t[(c2 + 2) * 16 + i] = vm.z;
    g_t[(c2 + 3) * 16 + i] = vm.w;
  }
  __syncthreads();

  const int o = tid;  // output column for z/r
  float az[ROWS], ar[ROWS];
  const float bz = ugb[o], br = rgb[o];
#pragma unroll
  for (int r = 0; r < ROWS; ++r) { az[r] = bz; ar[r] = br; }

  for (int c = 0; c < 2 * D; ++c) {
    float wz = ugWT[c * D + o];
    float wr = rgWT[c * D + o];
    const float4* gv = (const float4*)(g_t + c * 16);
    float4 g0 = gv[0], g1 = gv[1], g2 = gv[2], g3 = gv[3];
    float ga[16] = {g0.x, g0.y, g0.z, g0.w, g1.x, g1.y, g1.z, g1.w,
                    g2.x, g2.y, g2.z, g2.w, g3.x, g3.y, g3.z, g3.w};
#pragma unroll
    for (int r = 0; r < ROWS; ++r) {
      az[r] += ga[r] * wz;
      ar[r] += ga[r] * wr;
    }
  }

  // h column o for this block's rows (global, coalesced, L2-hot)
  float hcol[ROWS];
#pragma unroll
  for (int r = 0; r < ROWS; ++r) hcol[r] = h[(size_t)(row0 + r) * D + o];

  // z = sigmoid(az), r = sigmoid(ar); stash z back in az; write r*h to LDS
#pragma unroll
  for (int r = 0; r < ROWS; ++r) {
    float z = 1.0f / (1.0f + expf(-az[r]));
    float rg = 1.0f / (1.0f + expf(-ar[r]));
    az[r] = z;
    rh_t[o * 20 + r] = rg * hcol[r];
  }
  __syncthreads();

  // cand = tanh((r*h) @ CW); h = z*h + (1-z)*cand
  const int j = o;
  float ac[ROWS];
#pragma unroll
  for (int r = 0; r < ROWS; ++r) ac[r] = 0.0f;

  for (int k = 0; k < D; ++k) {
    float w = CW[k * D + j];
    const float4* rv = (const float4*)(rh_t + k * 20);
    float4 r0 = rv[0], r1 = rv[1], r2 = rv[2], r3 = rv[3];
    float ra[16] = {r0.x, r0.y, r0.z, r0.w, r1.x, r1.y, r1.z, r1.w,
                    r2.x, r2.y, r2.z, r2.w, r3.x, r3.y, r3.z, r3.w};
#pragma unroll
    for (int r = 0; r < ROWS; ++r) ac[r] += ra[r] * w;
  }

#pragma unroll
  for (int r = 0; r < ROWS; ++r) {
    float cand = tanhf(ac[r]);
    float z = az[r];
    h[(size_t)(row0 + r) * D + j] = z * hcol[r] + (1.0f - z) * cand;
  }
}

extern "C" void kernel_launch(void* const* d_in, const int* in_sizes, int n_in,
                              void* d_out, int out_size, void* d_ws, size_t ws_size,
                              hipStream_t stream) {
  const float* input = (const float*)d_in[0];
  const int* erow    = (const int*)d_in[1];
  const int* ecol    = (const int*)d_in[2];
  const float* ew    = (const float*)d_in[3];
  const float* W     = (const float*)d_in[4];
  const float* bias  = (const float*)d_in[5];
  const float* CW    = (const float*)d_in[6];
  const float* ugW   = (const float*)d_in[7];
  const float* ugb   = (const float*)d_in[8];
  const float* rgW   = (const float*)d_in[9];
  const float* rgb   = (const float*)d_in[10];

  float* h = (float*)d_out;  // h lives in d_out the whole time
  float* m = (float*)d_ws;   // [N, D] message accumulator
  float* ugWT = m + (size_t)NN * D;       // [256][128]
  float* rgWT = ugWT + 256 * 128;

  transpose_gates<<<256, 128, 0, stream>>>(ugW, rgW, ugWT, rgWT);
  init_h<<<NN / ROWS, 128, 0, stream>>>(input, W, bias, h);

  for (int step = 0; step < 3; ++step) {
    hipMemsetAsync(m, 0, (size_t)NN * D * sizeof(float), stream);
    spmm_scatter<<<4096, 256, 0, stream>>>(erow, ecol, ew, h, m);
    gate_update<<<NN / ROWS, 128, 0, stream>>>(m, ugWT, rgWT, ugb, rgb, CW, h);
  }
}

// Round 2
// 1411.661 us; speedup vs baseline: 3.4066x; 3.4066x over previous
//
#include <hip/hip_runtime.h>
#include <math.h>

#define NN 100000
#define EE 1600000
#define D 128
#define ROWS 16
#define NCHUNK ((NN + 255) / 256)   // 391

// ================= CSR binning (per call; edge order within a row is arbitrary) =================

__global__ __launch_bounds__(256) void k_hist(const int* __restrict__ erow, int* __restrict__ cnt) {
  int e = blockIdx.x * 256 + threadIdx.x;
  if (e < EE) atomicAdd(&cnt[erow[e]], 1);
}

__global__ __launch_bounds__(256) void k_chunk_sum(const int* __restrict__ cnt, int* __restrict__ csum) {
  __shared__ int s[256];
  int i = blockIdx.x * 256 + threadIdx.x;
  s[threadIdx.x] = (i < NN) ? cnt[i] : 0;
  __syncthreads();
  for (int d = 128; d > 0; d >>= 1) {
    if (threadIdx.x < d) s[threadIdx.x] += s[threadIdx.x + d];
    __syncthreads();
  }
  if (threadIdx.x == 0) csum[blockIdx.x] = s[0];
}

__global__ __launch_bounds__(512) void k_chunk_scan(const int* __restrict__ csum, int* __restrict__ coff) {
  __shared__ int s[512];
  int t = threadIdx.x;
  int v = (t < NCHUNK) ? csum[t] : 0;
  s[t] = v;
  __syncthreads();
  for (int d = 1; d < 512; d <<= 1) {
    int tv = (t >= d) ? s[t - d] : 0;
    __syncthreads();
    s[t] += tv;
    __syncthreads();
  }
  if (t < NCHUNK) coff[t] = s[t] - v;  // exclusive
}

__global__ __launch_bounds__(256) void k_row_start(const int* __restrict__ cnt, const int* __restrict__ coff,
                                                   int* __restrict__ row_start) {
  __shared__ int s[256];
  int i = blockIdx.x * 256 + threadIdx.x;
  int v = (i < NN) ? cnt[i] : 0;
  s[threadIdx.x] = v;
  __syncthreads();
  for (int d = 1; d < 256; d <<= 1) {
    int tv = (threadIdx.x >= d) ? s[threadIdx.x - d] : 0;
    __syncthreads();
    s[threadIdx.x] += tv;
    __syncthreads();
  }
  int excl = s[threadIdx.x] - v + coff[blockIdx.x];
  if (i < NN) row_start[i] = excl;
  if (i == NN - 1) row_start[NN] = excl + v;  // total = EE
}

__global__ __launch_bounds__(256) void k_scatter(const int* __restrict__ erow, const int* __restrict__ ecol,
                                                 const float* __restrict__ ew,
                                                 const int* __restrict__ row_start, int* __restrict__ cursor,
                                                 int* __restrict__ scol, float* __restrict__ sw) {
  int e = blockIdx.x * 256 + threadIdx.x;
  if (e >= EE) return;
  int r = erow[e];
  int pos = row_start[r] + atomicAdd(&cursor[r], 1);
  scol[pos] = ecol[e];
  sw[pos] = ew[e];
}

// ================= SpMM: m[row] = sum_e w_e * h[col_e], wave per row, no atomics =================

__global__ __launch_bounds__(256) void spmm_gather(
    const int* __restrict__ row_start, const int* __restrict__ scol, const float* __restrict__ sw,
    const float* __restrict__ h, float* __restrict__ m) {
  const int lane = threadIdx.x & 63;
  const int row = blockIdx.x * 4 + (threadIdx.x >> 6);
  if (row >= NN) return;
  const int s0 = row_start[row];
  const int n = row_start[row + 1] - s0;

  float2 acc0 = {0.f, 0.f}, acc1 = {0.f, 0.f};
  int k = 0;
  for (; k + 1 < n; k += 2) {
    int c0 = scol[s0 + k], c1 = scol[s0 + k + 1];
    float w0 = sw[s0 + k], w1 = sw[s0 + k + 1];
    float2 a = ((const float2*)(h + (size_t)c0 * D))[lane];
    float2 b = ((const float2*)(h + (size_t)c1 * D))[lane];
    acc0.x += w0 * a.x; acc0.y += w0 * a.y;
    acc1.x += w1 * b.x; acc1.y += w1 * b.y;
  }
  if (k < n) {
    int c = scol[s0 + k];
    float w = sw[s0 + k];
    float2 a = ((const float2*)(h + (size_t)c * D))[lane];
    acc0.x += w * a.x; acc0.y += w * a.y;
  }
  float2 out = {acc0.x + acc1.x, acc0.y + acc1.y};
  ((float2*)(m + (size_t)row * D))[lane] = out;
}

// ================= one-time: transpose gate weights [128][256] -> [256][128] =================
__global__ __launch_bounds__(128) void transpose_gates(
    const float* __restrict__ ugW, const float* __restrict__ rgW,
    float* __restrict__ ugWT, float* __restrict__ rgWT) {
  int c = blockIdx.x;      // 0..255
  int o = threadIdx.x;     // 0..127
  ugWT[c * 128 + o] = ugW[o * 256 + c];
  rgWT[c * 128 + o] = rgW[o * 256 + c];
}

// ================= h0 = X @ W + b =================
__global__ __launch_bounds__(128) void init_h(
    const float* __restrict__ X, const float* __restrict__ W,
    const float* __restrict__ b, float* __restrict__ h) {
  __shared__ float a_t[D * 16];
  const int row0 = blockIdx.x * ROWS;
  const int tid = threadIdx.x;
  const int i = tid & 15, cc = tid >> 4;

  const float4* xr = (const float4*)(X + (size_t)(row0 + i) * D);
#pragma unroll
  for (int u4 = 0; u4 < 4; ++u4) {
    float4 v = xr[cc * 4 + u4];
    int c = cc * 16 + u4 * 4;
    a_t[(c + 0) * 16 + i] = v.x;
    a_t[(c + 1) * 16 + i] = v.y;
    a_t[(c + 2) * 16 + i] = v.z;
    a_t[(c + 3) * 16 + i] = v.w;
  }
  __syncthreads();

  const int j = tid;
  float acc[ROWS];
  const float bj = b[j];
#pragma unroll
  for (int r = 0; r < ROWS; ++r) acc[r] = bj;

  for (int k = 0; k < D; ++k) {
    float w = W[k * D + j];
    const float4* av = (const float4*)(a_t + k * 16);
    float4 a0 = av[0], a1 = av[1], a2 = av[2], a3 = av[3];
    float ga[16] = {a0.x, a0.y, a0.z, a0.w, a1.x, a1.y, a1.z, a1.w,
                    a2.x, a2.y, a2.z, a2.w, a3.x, a3.y, a3.z, a3.w};
#pragma unroll
    for (int r = 0; r < ROWS; ++r) acc[r] += ga[r] * w;
  }
#pragma unroll
  for (int r = 0; r < ROWS; ++r) h[(size_t)(row0 + r) * D + j] = acc[r];
}

// ================= gates + candidate + in-place h update =================
__global__ __launch_bounds__(128) void gate_update(
    const float* __restrict__ m,
    const float* __restrict__ ugWT, const float* __restrict__ rgWT,
    const float* __restrict__ ugb, const float* __restrict__ rgb,
    const float* __restrict__ CW, float* __restrict__ h) {
  __shared__ float g_t[2 * D * 16];
  __shared__ float rh_t[D * 20];
  const int row0 = blockIdx.x * ROWS;
  const int tid = threadIdx.x;
  const int i = tid & 15, cc = tid >> 4;

  const float4* hr = (const float4*)(h + (size_t)(row0 + i) * D);
  const float4* mr = (const float4*)(m + (size_t)(row0 + i) * D);
#pragma unroll
  for (int u4 = 0; u4 < 4; ++u4) {
    float4 v = hr[cc * 4 + u4];
    int c = cc * 16 + u4 * 4;
    g_t[(c + 0) * 16 + i] = v.x;
    g_t[(c + 1) * 16 + i] = v.y;
    g_t[(c + 2) * 16 + i] = v.z;
    g_t[(c + 3) * 16 + i] = v.w;
    float4 vm = mr[cc * 4 + u4];
    int c2 = D + c;
    g_t[(c2 + 0) * 16 + i] = vm.x;
    g_t[(c2 + 1) * 16 + i] = vm.y;
    g_t[(c2 + 2) * 16 + i] = vm.z;
    g_t[(c2 + 3) * 16 + i] = vm.w;
  }
  __syncthreads();

  const int o = tid;
  float az[ROWS], ar[ROWS];
  const float bz = ugb[o], br = rgb[o];
#pragma unroll
  for (int r = 0; r < ROWS; ++r) { az[r] = bz; ar[r] = br; }

  for (int c = 0; c < 2 * D; ++c) {
    float wz = ugWT[c * D + o];
    float wr = rgWT[c * D + o];
    const float4* gv = (const float4*)(g_t + c * 16);
    float4 g0 = gv[0], g1 = gv[1], g2 = gv[2], g3 = gv[3];
    float ga[16] = {g0.x, g0.y, g0.z, g0.w, g1.x, g1.y, g1.z, g1.w,
                    g2.x, g2.y, g2.z, g2.w, g3.x, g3.y, g3.z, g3.w};
#pragma unroll
    for (int r = 0; r < ROWS; ++r) {
      az[r] += ga[r] * wz;
      ar[r] += ga[r] * wr;
    }
  }

  float hcol[ROWS];
#pragma unroll
  for (int r = 0; r < ROWS; ++r) hcol[r] = h[(size_t)(row0 + r) * D + o];

#pragma unroll
  for (int r = 0; r < ROWS; ++r) {
    float z = 1.0f / (1.0f + expf(-az[r]));
    float rg = 1.0f / (1.0f + expf(-ar[r]));
    az[r] = z;
    rh_t[o * 20 + r] = rg * hcol[r];
  }
  __syncthreads();

  const int j = o;
  float ac[ROWS];
#pragma unroll
  for (int r = 0; r < ROWS; ++r) ac[r] = 0.0f;

  for (int k = 0; k < D; ++k) {
    float w = CW[k * D + j];
    const float4* rv = (const float4*)(rh_t + k * 20);
    float4 r0 = rv[0], r1 = rv[1], r2 = rv[2], r3 = rv[3];
    float ra[16] = {r0.x, r0.y, r0.z, r0.w, r1.x, r1.y, r1.z, r1.w,
                    r2.x, r2.y, r2.z, r2.w, r3.x, r3.y, r3.z, r3.w};
#pragma unroll
    for (int r = 0; r < ROWS; ++r) ac[r] += ra[r] * w;
  }

#pragma unroll
  for (int r = 0; r < ROWS; ++r) {
    float cand = tanhf(ac[r]);
    float z = az[r];
    h[(size_t)(row0 + r) * D + j] = z * hcol[r] + (1.0f - z) * cand;
  }
}

extern "C" void kernel_launch(void* const* d_in, const int* in_sizes, int n_in,
                              void* d_out, int out_size, void* d_ws, size_t ws_size,
                              hipStream_t stream) {
  const float* input = (const float*)d_in[0];
  const int* erow    = (const int*)d_in[1];
  const int* ecol    = (const int*)d_in[2];
  const float* ew    = (const float*)d_in[3];
  const float* W     = (const float*)d_in[4];
  const float* bias  = (const float*)d_in[5];
  const float* CW    = (const float*)d_in[6];
  const float* ugW   = (const float*)d_in[7];
  const float* ugb   = (const float*)d_in[8];
  const float* rgW   = (const float*)d_in[9];
  const float* rgb   = (const float*)d_in[10];

  float* h = (float*)d_out;  // h lives in d_out the whole time

  // ---- workspace carve-up (~65.6 MB) ----
  char* ws = (char*)d_ws;
  float* m         = (float*)ws;                 ws += (size_t)NN * D * sizeof(float);   // 51.2 MB
  float* ugWT      = (float*)ws;                 ws += 256 * 128 * sizeof(float);
  float* rgWT      = (float*)ws;                 ws += 256 * 128 * sizeof(float);
  int*   cnt       = (int*)ws;                   ws += NN * sizeof(int);                 // also reused as cursor
  int*   row_start = (int*)ws;                   ws += (NN + 1) * sizeof(int);
  int*   csum      = (int*)ws;                   ws += 512 * sizeof(int);
  int*   coff      = (int*)ws;                   ws += 512 * sizeof(int);
  int*   scol      = (int*)ws;                   ws += (size_t)EE * sizeof(int);         // 6.4 MB
  float* sw        = (float*)ws;                 ws += (size_t)EE * sizeof(float);       // 6.4 MB

  // ---- CSR binning (once per call) ----
  hipMemsetAsync(cnt, 0, NN * sizeof(int), stream);
  k_hist<<<(EE + 255) / 256, 256, 0, stream>>>(erow, cnt);
  k_chunk_sum<<<NCHUNK, 256, 0, stream>>>(cnt, csum);
  k_chunk_scan<<<1, 512, 0, stream>>>(csum, coff);
  k_row_start<<<NCHUNK, 256, 0, stream>>>(cnt, coff, row_start);
  hipMemsetAsync(cnt, 0, NN * sizeof(int), stream);  // reuse as cursor
  k_scatter<<<(EE + 255) / 256, 256, 0, stream>>>(erow, ecol, ew, row_start, cnt, scol, sw);

  transpose_gates<<<256, 128, 0, stream>>>(ugW, rgW, ugWT, rgWT);
  init_h<<<NN / ROWS, 128, 0, stream>>>(input, W, bias, h);

  for (int step = 0; step < 3; ++step) {
    spmm_gather<<<(NN + 3) / 4, 256, 0, stream>>>(row_start, scol, sw, h, m);
    gate_update<<<NN / ROWS, 128, 0, stream>>>(m, ugWT, rgWT, ugb, rgb, CW, h);
  }
}

// Round 3
// 836.706 us; speedup vs baseline: 5.7475x; 1.6872x over previous
//
#include <hip/hip_runtime.h>
#include <math.h>

#define NN 100000
#define EE 1600000
#define D 128
#define NCHUNK ((NN + 255) / 256)   // 391

typedef __attribute__((ext_vector_type(8))) short short8;
typedef __attribute__((ext_vector_type(4))) float floatx4;

// ---------- helpers ----------
static __device__ __forceinline__ unsigned short f2bf(float f) {
  unsigned int u = __builtin_bit_cast(unsigned int, f);
  u = (u + 0x7fff + ((u >> 16) & 1)) >> 16;   // RNE
  return (unsigned short)u;
}
static __device__ __forceinline__ float bflo(unsigned int u) {  // element 0 (low 16)
  return __builtin_bit_cast(float, u << 16);
}
static __device__ __forceinline__ float bfhi(unsigned int u) {  // element 1 (high 16)
  return __builtin_bit_cast(float, u & 0xffff0000u);
}
static __device__ __forceinline__ float bf2f(unsigned short s) {
  return __builtin_bit_cast(float, (unsigned int)s << 16);
}
static __device__ __forceinline__ float sig_f(float x) { return 1.f / (1.f + __expf(-x)); }
static __device__ __forceinline__ float tanh_f(float x) {
  float e = __expf(2.f * x);
  return 1.f - 2.f / (e + 1.f);
}

// ================= CSR binning (unchanged from R2) =================

__global__ __launch_bounds__(256) void k_hist(const int* __restrict__ erow, int* __restrict__ cnt) {
  int e = blockIdx.x * 256 + threadIdx.x;
  if (e < EE) atomicAdd(&cnt[erow[e]], 1);
}

__global__ __launch_bounds__(256) void k_chunk_sum(const int* __restrict__ cnt, int* __restrict__ csum) {
  __shared__ int s[256];
  int i = blockIdx.x * 256 + threadIdx.x;
  s[threadIdx.x] = (i < NN) ? cnt[i] : 0;
  __syncthreads();
  for (int d = 128; d > 0; d >>= 1) {
    if (threadIdx.x < d) s[threadIdx.x] += s[threadIdx.x + d];
    __syncthreads();
  }
  if (threadIdx.x == 0) csum[blockIdx.x] = s[0];
}

__global__ __launch_bounds__(512) void k_chunk_scan(const int* __restrict__ csum, int* __restrict__ coff) {
  __shared__ int s[512];
  int t = threadIdx.x;
  int v = (t < NCHUNK) ? csum[t] : 0;
  s[t] = v;
  __syncthreads();
  for (int d = 1; d < 512; d <<= 1) {
    int tv = (t >= d) ? s[t - d] : 0;
    __syncthreads();
    s[t] += tv;
    __syncthreads();
  }
  if (t < NCHUNK) coff[t] = s[t] - v;  // exclusive
}

__global__ __launch_bounds__(256) void k_row_start(const int* __restrict__ cnt, const int* __restrict__ coff,
                                                   int* __restrict__ row_start) {
  __shared__ int s[256];
  int i = blockIdx.x * 256 + threadIdx.x;
  int v = (i < NN) ? cnt[i] : 0;
  s[threadIdx.x] = v;
  __syncthreads();
  for (int d = 1; d < 256; d <<= 1) {
    int tv = (threadIdx.x >= d) ? s[threadIdx.x - d] : 0;
    __syncthreads();
    s[threadIdx.x] += tv;
    __syncthreads();
  }
  int excl = s[threadIdx.x] - v + coff[blockIdx.x];
  if (i < NN) row_start[i] = excl;
  if (i == NN - 1) row_start[NN] = excl + v;
}

__global__ __launch_bounds__(256) void k_scatter(const int* __restrict__ erow, const int* __restrict__ ecol,
                                                 const float* __restrict__ ew,
                                                 const int* __restrict__ row_start, int* __restrict__ cursor,
                                                 int* __restrict__ scol, float* __restrict__ sw) {
  int e = blockIdx.x * 256 + threadIdx.x;
  if (e >= EE) return;
  int r = erow[e];
  int pos = row_start[r] + atomicAdd(&cursor[r], 1);
  scol[pos] = ecol[e];
  sw[pos] = ew[e];
}

// ================= weight packing into MFMA B-fragment order (once per call) =================
// b_frag[lane][j] = W_zr[o = nt*16 + (lane&15)][c = ks*32 + (lane>>4)*8 + j]
__global__ __launch_bounds__(64) void k_pack_zr(const float* __restrict__ ugW, const float* __restrict__ rgW,
                                                unsigned int* __restrict__ packZR) {
  int g = blockIdx.x;           // g = nt*8 + ks, nt 0..15, ks 0..7
  int nt = g >> 3, ks = g & 7;
  int lane = threadIdx.x;
  int o = nt * 16 + (lane & 15);
  int c0 = ks * 32 + (lane >> 4) * 8;
  const float* src = (o < 128 ? ugW + (size_t)o * 256 : rgW + (size_t)(o - 128) * 256) + c0;
  float4 f0 = ((const float4*)src)[0];
  float4 f1 = ((const float4*)src)[1];
  uint4 out;
  out.x = (unsigned int)f2bf(f0.x) | ((unsigned int)f2bf(f0.y) << 16);
  out.y = (unsigned int)f2bf(f0.z) | ((unsigned int)f2bf(f0.w) << 16);
  out.z = (unsigned int)f2bf(f1.x) | ((unsigned int)f2bf(f1.y) << 16);
  out.w = (unsigned int)f2bf(f1.z) | ((unsigned int)f2bf(f1.w) << 16);
  ((uint4*)packZR)[g * 64 + lane] = out;
}

// b_frag[lane][j] = CW[k = ks*32 + (lane>>4)*8 + j][n = nt*16 + (lane&15)]
__global__ __launch_bounds__(64) void k_pack_cw(const float* __restrict__ CW, unsigned int* __restrict__ packCW) {
  int g = blockIdx.x;           // g = nt*4 + ks, nt 0..7, ks 0..3
  int nt = g >> 2, ks = g & 3;
  int lane = threadIdx.x;
  int n = nt * 16 + (lane & 15);
  int k0 = ks * 32 + (lane >> 4) * 8;
  unsigned short v[8];
#pragma unroll
  for (int j = 0; j < 8; ++j) v[j] = f2bf(CW[(size_t)(k0 + j) * 128 + n]);
  uint4 out;
  out.x = (unsigned int)v[0] | ((unsigned int)v[1] << 16);
  out.y = (unsigned int)v[2] | ((unsigned int)v[3] << 16);
  out.z = (unsigned int)v[4] | ((unsigned int)v[5] << 16);
  out.w = (unsigned int)v[6] | ((unsigned int)v[7] << 16);
  ((uint4*)packCW)[g * 64 + lane] = out;
}

// ================= h0 = X @ W + b (fp32), also writes bf16 mirror =================
__global__ __launch_bounds__(128) void init_h(
    const float* __restrict__ X, const float* __restrict__ W,
    const float* __restrict__ b, float* __restrict__ h, unsigned short* __restrict__ h_bf) {
  __shared__ float a_t[D * 16];
  const int row0 = blockIdx.x * 16;
  const int tid = threadIdx.x;
  const int i = tid & 15, cc = tid >> 4;

  const float4* xr = (const float4*)(X + (size_t)(row0 + i) * D);
#pragma unroll
  for (int u4 = 0; u4 < 4; ++u4) {
    float4 v = xr[cc * 4 + u4];
    int c = cc * 16 + u4 * 4;
    a_t[(c + 0) * 16 + i] = v.x;
    a_t[(c + 1) * 16 + i] = v.y;
    a_t[(c + 2) * 16 + i] = v.z;
    a_t[(c + 3) * 16 + i] = v.w;
  }
  __syncthreads();

  const int j = tid;
  float acc[16];
  const float bj = b[j];
#pragma unroll
  for (int r = 0; r < 16; ++r) acc[r] = bj;

  for (int k = 0; k < D; ++k) {
    float w = W[k * D + j];
    const float4* av = (const float4*)(a_t + k * 16);
    float4 a0 = av[0], a1 = av[1], a2 = av[2], a3 = av[3];
    float ga[16] = {a0.x, a0.y, a0.z, a0.w, a1.x, a1.y, a1.z, a1.w,
                    a2.x, a2.y, a2.z, a2.w, a3.x, a3.y, a3.z, a3.w};
#pragma unroll
    for (int r = 0; r < 16; ++r) acc[r] += ga[r] * w;
  }
#pragma unroll
  for (int r = 0; r < 16; ++r) {
    size_t gi = (size_t)(row0 + r) * D + j;
    h[gi] = acc[r];
    h_bf[gi] = f2bf(acc[r]);
  }
}

// ================= SpMM: m_bf[row] = sum_e w_e * h_bf[col_e] (fp32 accumulate) =================
__global__ __launch_bounds__(256) void spmm_gather_bf(
    const int* __restrict__ row_start, const int* __restrict__ scol, const float* __restrict__ sw,
    const unsigned int* __restrict__ h_bf_u, unsigned int* __restrict__ m_bf_u) {
  const int lane = threadIdx.x & 63;
  const int row = blockIdx.x * 4 + (threadIdx.x >> 6);
  if (row >= NN) return;
  const int s0 = row_start[row];
  const int n = row_start[row + 1] - s0;

  float a0 = 0.f, a1 = 0.f, b0 = 0.f, b1 = 0.f;
  int k = 0;
  for (; k + 1 < n; k += 2) {
    int c0 = scol[s0 + k], c1 = scol[s0 + k + 1];
    float w0 = sw[s0 + k], w1 = sw[s0 + k + 1];
    unsigned int u0 = h_bf_u[(size_t)c0 * 64 + lane];
    unsigned int u1 = h_bf_u[(size_t)c1 * 64 + lane];
    a0 += w0 * bflo(u0); a1 += w0 * bfhi(u0);
    b0 += w1 * bflo(u1); b1 += w1 * bfhi(u1);
  }
  if (k < n) {
    int c = scol[s0 + k];
    float w = sw[s0 + k];
    unsigned int u = h_bf_u[(size_t)c * 64 + lane];
    a0 += w * bflo(u); a1 += w * bfhi(u);
  }
  unsigned int out = (unsigned int)f2bf(a0 + b0) | ((unsigned int)f2bf(a1 + b1) << 16);
  m_bf_u[(size_t)row * 64 + lane] = out;
}

// ================= fused gates + candidate + h update, bf16 MFMA =================
// block: 256 thr (4 waves), 32 rows. waves: mh=w&1 (row half), nh=w>>1 (col half).
__global__ __launch_bounds__(256) void gate_mfma(
    const unsigned short* __restrict__ h_bf, const unsigned short* __restrict__ m_bf,
    const short* __restrict__ packZR, const short* __restrict__ packCW,
    const float* __restrict__ ugb, const float* __restrict__ rgb,
    float* __restrict__ h, unsigned short* __restrict__ h_bf_out) {
  __shared__ __align__(16) short sA[32 * 264];    // [row][c 0..255], stride 264 bf16
  __shared__ __align__(16) short sRH[32 * 136];   // [row][k 0..127], stride 136 bf16
  __shared__ float sZ[32 * 132];                  // [row][o 0..127], stride 132 f32

  const int tid = threadIdx.x;
  const int row0 = blockIdx.x * 32;

  // ---- stage A = [h | m] bf16 tile ----
  for (int idx = tid; idx < 512; idx += 256) {
    int r = idx >> 4, ch = idx & 15;
    const uint4* ph = (const uint4*)(h_bf + (size_t)(row0 + r) * D);
    const uint4* pm = (const uint4*)(m_bf + (size_t)(row0 + r) * D);
    *(uint4*)(sA + r * 264 + ch * 8) = ph[ch];
    *(uint4*)(sA + r * 264 + 128 + ch * 8) = pm[ch];
  }
  __syncthreads();

  const int wave = tid >> 6, lane = tid & 63;
  const int quad = lane >> 4, l15 = lane & 15;
  const int mh = wave & 1, nh = wave >> 1;
  const int mrow = mh * 16 + l15;

  // ---- z/r: [32x256] @ [256x256] ----
  floatx4 acc[8];
  const floatx4 zero4 = {0.f, 0.f, 0.f, 0.f};
#pragma unroll
  for (int t = 0; t < 8; ++t) acc[t] = zero4;

  const short8* pB = (const short8*)packZR;
#pragma unroll
  for (int ks = 0; ks < 8; ++ks) {
    short8 a = *(const short8*)(sA + mrow * 264 + ks * 32 + quad * 8);
#pragma unroll
    for (int t = 0; t < 8; ++t) {
      short8 b = pB[((nh * 8 + t) * 8 + ks) * 64 + lane];
      acc[t] = __builtin_amdgcn_mfma_f32_16x16x32_bf16(a, b, acc[t], 0, 0, 0);
    }
  }

  if (nh == 0) {  // z: sigmoid -> sZ
#pragma unroll
    for (int t = 0; t < 8; ++t) {
      int col = t * 16 + l15;
      float bv = ugb[col];
#pragma unroll
      for (int reg = 0; reg < 4; ++reg) {
        int row = mh * 16 + quad * 4 + reg;
        sZ[row * 132 + col] = sig_f(acc[t][reg] + bv);
      }
    }
  } else {  // r: sigmoid, rh = r * h_bf -> sRH
#pragma unroll
    for (int t = 0; t < 8; ++t) {
      int col = t * 16 + l15;
      float bv = rgb[col];
#pragma unroll
      for (int reg = 0; reg < 4; ++reg) {
        int row = mh * 16 + quad * 4 + reg;
        float rr = sig_f(acc[t][reg] + bv);
        float hv = bf2f((unsigned short)sA[row * 264 + col]);
        sRH[row * 136 + col] = (short)f2bf(rr * hv);
      }
    }
  }
  __syncthreads();

  // ---- cand: [32x128] @ [128x128]; wave covers rows mh*16.., cols nh*64.. ----
  floatx4 acc2[4];
#pragma unroll
  for (int t = 0; t < 4; ++t) acc2[t] = zero4;

  const short8* pC = (const short8*)packCW;
#pragma unroll
  for (int ks = 0; ks < 4; ++ks) {
    short8 a = *(const short8*)(sRH + mrow * 136 + ks * 32 + quad * 8);
#pragma unroll
    for (int t = 0; t < 4; ++t) {
      short8 b = pC[((nh * 4 + t) * 4 + ks) * 64 + lane];
      acc2[t] = __builtin_amdgcn_mfma_f32_16x16x32_bf16(a, b, acc2[t], 0, 0, 0);
    }
  }

  // ---- epilogue: h = z*h + (1-z)*tanh(cand) ----
#pragma unroll
  for (int t = 0; t < 4; ++t) {
    int col = nh * 64 + t * 16 + l15;
#pragma unroll
    for (int reg = 0; reg < 4; ++reg) {
      int row = mh * 16 + quad * 4 + reg;
      float cand = tanh_f(acc2[t][reg]);
      float z = sZ[row * 132 + col];
      size_t gi = (size_t)(row0 + row) * D + col;
      float hold = h[gi];
      float hn = z * hold + (1.f - z) * cand;
      h[gi] = hn;
      h_bf_out[gi] = f2bf(hn);
    }
  }
}

extern "C" void kernel_launch(void* const* d_in, const int* in_sizes, int n_in,
                              void* d_out, int out_size, void* d_ws, size_t ws_size,
                              hipStream_t stream) {
  const float* input = (const float*)d_in[0];
  const int* erow    = (const int*)d_in[1];
  const int* ecol    = (const int*)d_in[2];
  const float* ew    = (const float*)d_in[3];
  const float* W     = (const float*)d_in[4];
  const float* bias  = (const float*)d_in[5];
  const float* CW    = (const float*)d_in[6];
  const float* ugW   = (const float*)d_in[7];
  const float* ugb   = (const float*)d_in[8];
  const float* rgW   = (const float*)d_in[9];
  const float* rgb   = (const float*)d_in[10];

  float* h = (float*)d_out;

  // ---- workspace carve-up (~65 MB) ----
  char* ws = (char*)d_ws;
  unsigned short* h_bf = (unsigned short*)ws; ws += (size_t)NN * D * 2;   // 25.6 MB
  unsigned short* m_bf = (unsigned short*)ws; ws += (size_t)NN * D * 2;   // 25.6 MB
  unsigned int* packZR = (unsigned int*)ws;   ws += 16 * 8 * 64 * 16;     // 128 KB
  unsigned int* packCW = (unsigned int*)ws;   ws += 8 * 4 * 64 * 16;      // 32 KB
  int* cnt       = (int*)ws;                  ws += NN * sizeof(int);
  int* row_start = (int*)ws;                  ws += (NN + 1) * sizeof(int);
  int* csum      = (int*)ws;                  ws += 512 * sizeof(int);
  int* coff      = (int*)ws;                  ws += 512 * sizeof(int);
  int* scol      = (int*)ws;                  ws += (size_t)EE * sizeof(int);
  float* sw      = (float*)ws;                ws += (size_t)EE * sizeof(float);

  // ---- CSR binning ----
  hipMemsetAsync(cnt, 0, NN * sizeof(int), stream);
  k_hist<<<(EE + 255) / 256, 256, 0, stream>>>(erow, cnt);
  k_chunk_sum<<<NCHUNK, 256, 0, stream>>>(cnt, csum);
  k_chunk_scan<<<1, 512, 0, stream>>>(csum, coff);
  k_row_start<<<NCHUNK, 256, 0, stream>>>(cnt, coff, row_start);
  hipMemsetAsync(cnt, 0, NN * sizeof(int), stream);
  k_scatter<<<(EE + 255) / 256, 256, 0, stream>>>(erow, ecol, ew, row_start, cnt, scol, sw);

  // ---- weight packing + init ----
  k_pack_zr<<<128, 64, 0, stream>>>(ugW, rgW, packZR);
  k_pack_cw<<<32, 64, 0, stream>>>(CW, packCW);
  init_h<<<NN / 16, 128, 0, stream>>>(input, W, bias, h, h_bf);

  for (int step = 0; step < 3; ++step) {
    spmm_gather_bf<<<(NN + 3) / 4, 256, 0, stream>>>(row_start, scol, sw,
                                                     (const unsigned int*)h_bf, (unsigned int*)m_bf);
    gate_mfma<<<NN / 32, 256, 0, stream>>>(h_bf, m_bf, (const short*)packZR, (const short*)packCW,
                                           ugb, rgb, h, h_bf);
  }
}